// Round 2
// baseline (581.410 us; speedup 1.0000x reference)
//
#include <hip/hip_runtime.h>

// NoisyTopExpertsPerItemRouter: G=32,S=1024,H=2048,E=64,K=2 (top-2)
// Outputs (concat, f32): idx (N*2) | w (N*2) | aux (1) | probs (N*64)

constexpr int GS  = 32768;
constexpr int EXP = 64;
constexpr int HID = 2048;
constexpr int BM  = 64;   // rows per block (lane = row)
constexpr int BK  = 32;   // K chunk

__global__ __launch_bounds__(256, 2)
void router_kernel(const float* __restrict__ tokens,
                   const float* __restrict__ noise,
                   const float* __restrict__ W,
                   const float* __restrict__ bias,
                   float* __restrict__ out,
                   float* __restrict__ ws)
{
    // stride 33 floats: bank = (row + k) % 32 -> 2-way (free) for the
    // column-slice read a[k] = As[lane][k]. b32 access only (33*4 B rows
    // are not 16B-aligned; b128 here would be 8-way conflicted anyway).
    __shared__ float As[2][BM][BK + 1];
    __shared__ float lg[BM][EXP + 1];
    __shared__ float red[8][EXP];

    const int tid  = threadIdx.x;
    const int lane = tid & 63;
    const int wid  = tid >> 6;
    const int row0 = blockIdx.x * BM;

    // wave-uniform expert base -> W addresses provably uniform -> s_load
    const int e0 = __builtin_amdgcn_readfirstlane(wid) << 4;

    // staging: thread (sr, sc) loads 8 floats of row sr
    const int sr = tid >> 2;
    const int sc = (tid & 3) << 3;

    const float* Arow  = tokens + (size_t)(row0 + sr) * HID + sc;
    const float* Wbase = W + (size_t)e0 * HID;

    double accd[16];
    #pragma unroll
    for (int e = 0; e < 16; ++e) accd[e] = 0.0;

    // prologue: stage chunk 0
    float4 p0 = *(const float4*)(Arow);
    float4 p1 = *(const float4*)(Arow + 4);
    {
        float t[8] = {p0.x,p0.y,p0.z,p0.w,p1.x,p1.y,p1.z,p1.w};
        #pragma unroll
        for (int i = 0; i < 8; ++i) As[0][sr][sc + i] = t[i];
    }
    __syncthreads();

    for (int kb = 0; kb < HID; kb += BK) {
        const int buf = (kb >> 5) & 1;

        // T14: issue next chunk's global loads before compute
        if (kb + BK < HID) {
            p0 = *(const float4*)(Arow + kb + BK);
            p1 = *(const float4*)(Arow + kb + BK + 4);
        }

        // per-lane A fragment (row = lane), reused across 16 experts
        float a[BK];
        #pragma unroll
        for (int k = 0; k < BK; ++k) a[k] = As[buf][lane][k];

        float facc[16];
        #pragma unroll
        for (int e = 0; e < 16; ++e) facc[e] = 0.f;

        #pragma unroll
        for (int ks = 0; ks < BK; ks += 16) {
            #pragma unroll 4
            for (int e = 0; e < 16; ++e) {
                const float* wr = Wbase + (size_t)e * HID + kb + ks; // uniform -> SGPR
                float c0 = 0.f, c1 = 0.f;
                #pragma unroll
                for (int k = 0; k < 16; k += 2) {
                    c0 = fmaf(wr[k],     a[ks + k],     c0);
                    c1 = fmaf(wr[k + 1], a[ks + k + 1], c1);
                }
                facc[e] += c0 + c1;
            }
        }
        // fold chunk into f64 (keeps logit error ~4e-8 so top-2 ordering
        // matches the high-precision reference)
        #pragma unroll
        for (int e = 0; e < 16; ++e) accd[e] += (double)facc[e];

        // write prefetched chunk into the other buffer; one barrier/chunk
        if (kb + BK < HID) {
            float t[8] = {p0.x,p0.y,p0.z,p0.w,p1.x,p1.y,p1.z,p1.w};
            #pragma unroll
            for (int i = 0; i < 8; ++i) As[buf ^ 1][sr][sc + i] = t[i];
        }
        __syncthreads();
    }

    // gather logits: lane l holds row l, experts e0..e0+15
    #pragma unroll
    for (int e = 0; e < 16; ++e) lg[lane][e0 + e] = (float)accd[e];
    __syncthreads();

    // ---- per-row epilogue: 4 waves x 16 rows (unchanged, proven) ----
    float* out_idx   = out;
    float* out_w     = out + 2 * GS;
    float* out_probs = out + 4 * GS + 1;

    const float blane = bias[lane];
    float impL = 0.f, cntL = 0.f;

    for (int rr = 0; rr < 16; ++rr) {
        const int r = (wid << 4) + rr;
        const size_t row = (size_t)row0 + r;
        float v = lg[r][lane] + blane + noise[row * EXP + lane];

        float m = v;
        #pragma unroll
        for (int off = 32; off >= 1; off >>= 1)
            m = fmaxf(m, __shfl_xor(m, off));
        float e = expf(v - m);
        float s = e;
        #pragma unroll
        for (int off = 32; off >= 1; off >>= 1)
            s += __shfl_xor(s, off);
        float p = e / s;

        out_probs[row * EXP + lane] = p;
        impL += p;
        cntL += (p > 0.f) ? 1.f : 0.f;

        float v1 = p; int i1 = lane;
        #pragma unroll
        for (int off = 32; off >= 1; off >>= 1) {
            float ov = __shfl_xor(v1, off);
            int   oi = __shfl_xor(i1, off);
            if (ov > v1 || (ov == v1 && oi < i1)) { v1 = ov; i1 = oi; }
        }
        float v2 = (lane == i1) ? -1.f : p; int i2 = lane;
        #pragma unroll
        for (int off = 32; off >= 1; off >>= 1) {
            float ov = __shfl_xor(v2, off);
            int   oi = __shfl_xor(i2, off);
            if (ov > v2 || (ov == v2 && oi < i2)) { v2 = ov; i2 = oi; }
        }
        if (lane == 0) {
            float denom = v1 + v2 + 1e-9f;
            out_idx[row * 2 + 0] = (float)i1;
            out_idx[row * 2 + 1] = (float)i2;
            out_w[row * 2 + 0] = v1 / denom;
            out_w[row * 2 + 1] = v2 / denom;
        }
    }

    red[wid][lane]     = impL;
    red[4 + wid][lane] = cntL;
    __syncthreads();
    if (tid < EXP) {
        float t1 = red[0][tid] + red[1][tid] + red[2][tid] + red[3][tid];
        float t2 = red[4][tid] + red[5][tid] + red[6][tid] + red[7][tid];
        atomicAdd(&ws[tid], t1);
        atomicAdd(&ws[EXP + tid], t2);
    }
}

__global__ void aux_kernel(const float* __restrict__ ws, float* __restrict__ out)
{
    const int lane = threadIdx.x;  // 64 threads
    float x = ws[lane] * ws[EXP + lane];   // importance * load
    float s = x;
    #pragma unroll
    for (int off = 32; off >= 1; off >>= 1)
        s += __shfl_xor(s, off);
    float mean = s * (1.f / 64.f);
    float d = x - mean;
    float ss = d * d;
    #pragma unroll
    for (int off = 32; off >= 1; off >>= 1)
        ss += __shfl_xor(ss, off);
    if (lane == 0)
        out[4 * GS] = 0.01f * (ss / 63.f);   // unbiased var * 0.01
}

extern "C" void kernel_launch(void* const* d_in, const int* in_sizes, int n_in,
                              void* d_out, int out_size, void* d_ws, size_t ws_size,
                              hipStream_t stream)
{
    const float* tokens = (const float*)d_in[0];
    const float* noise  = (const float*)d_in[1];
    const float* W      = (const float*)d_in[2];
    const float* bias   = (const float*)d_in[3];
    float* out = (float*)d_out;
    float* ws  = (float*)d_ws;

    hipMemsetAsync(ws, 0, 2 * EXP * sizeof(float), stream);
    router_kernel<<<GS / BM, 256, 0, stream>>>(tokens, noise, W, bias, out, ws);
    aux_kernel<<<1, 64, 0, stream>>>(ws, out);
}

// Round 3
// 121.634 us; speedup vs baseline: 4.7800x; 4.7800x over previous
//
#include <hip/hip_runtime.h>

// NoisyTopExpertsPerItemRouter: G=32,S=1024,H=2048,E=64,K=2 (top-2)
// Outputs (concat, f32): idx (N*2) | w (N*2) | aux (1) | probs (N*64)
//
// GEMM via bf16 split-precision MFMA:
//   a = ah + 2^-8 * amS,  w = wh + 2^-8 * wmS   (bf16: no denormal risk)
//   logits = accM(ah*wh) + 2^-8 * accS(ah*wmS + amS*wh)
// Dropped cross terms are <= 2^-18 relative -> f32-grade logits.

constexpr int GS  = 32768;
constexpr int EXP = 64;
constexpr int HID = 2048;
constexpr int BM  = 64;   // rows per block
constexpr int BK  = 32;   // K chunk

typedef __attribute__((ext_vector_type(8))) short s16x8;
typedef __attribute__((ext_vector_type(4))) float f32x4;

__device__ __forceinline__ unsigned short f2bf(float x) {
    union { float f; unsigned u; } v; v.f = x;
    unsigned r = v.u + 0x7fffu + ((v.u >> 16) & 1u);   // RNE
    return (unsigned short)(r >> 16);
}
__device__ __forceinline__ float bf2f(unsigned short h) {
    union { unsigned u; float f; } v; v.u = ((unsigned)h) << 16; return v.f;
}

// decompose 8 f32 -> bf16 hi + 2^8-scaled bf16 mid, write fragment-linear LDS
__device__ __forceinline__ void dwrite(short* __restrict__ H, short* __restrict__ M,
                                       int slot, float4 x0, float4 x1) {
    float v[8] = {x0.x, x0.y, x0.z, x0.w, x1.x, x1.y, x1.z, x1.w};
    s16x8 h, m;
    #pragma unroll
    for (int i = 0; i < 8; ++i) {
        unsigned short hb = f2bf(v[i]);
        float r = (v[i] - bf2f(hb)) * 256.f;
        h[i] = (short)hb;
        m[i] = (short)f2bf(r);
    }
    *(s16x8*)&H[slot] = h;
    *(s16x8*)&M[slot] = m;
}

__global__ __launch_bounds__(256)
void router_kernel(const float* __restrict__ tokens,
                   const float* __restrict__ noise,
                   const float* __restrict__ Wg,
                   const float* __restrict__ bias,
                   float* __restrict__ out,
                   float* __restrict__ ws)
{
    // fragment-linear tiles: [mt|nt][kg][16 rows|cols][8 k] bf16, 4KB each
    __shared__ short Ah[2][BM * BK], Am[2][BM * BK];
    __shared__ short Wh[2][EXP * BK], Wm[2][EXP * BK];
    __shared__ float lg[BM][EXP + 1];
    __shared__ float red[8][EXP];

    const int tid  = threadIdx.x;
    const int lane = tid & 63;
    const int wv   = tid >> 6;          // wave id = A m-tile
    const int row0 = blockIdx.x * BM;

    // staging: thread -> (row/expert = tid>>2, k-group = tid&3), 8 f32 each
    const int srow = tid >> 2;
    const int skg  = tid & 3;
    const int slot = (((srow >> 4) * 4 + skg) * 16 + (srow & 15)) * 8;

    const float* Ap = tokens + (size_t)(row0 + srow) * HID + skg * 8;
    const float* Wp = Wg     + (size_t)srow          * HID + skg * 8;

    f32x4 accM[4], accS[4];
    #pragma unroll
    for (int nt = 0; nt < 4; ++nt) {
        accM[nt] = (f32x4)0.f;
        accS[nt] = (f32x4)0.f;
    }

    // prologue: stage chunk 0
    float4 a0 = *(const float4*)(Ap);
    float4 a1 = *(const float4*)(Ap + 4);
    float4 w0 = *(const float4*)(Wp);
    float4 w1 = *(const float4*)(Wp + 4);
    dwrite(Ah[0], Am[0], slot, a0, a1);
    dwrite(Wh[0], Wm[0], slot, w0, w1);
    __syncthreads();

    const int afo = (wv * 64 + lane) * 8;   // A frag: base + lane*16B, conflict-free

    for (int kb = 0; kb < HID; kb += BK) {
        const int  buf  = (kb >> 5) & 1;
        const bool more = (kb + BK < HID);

        if (more) {   // issue next chunk's global loads before compute (T14)
            a0 = *(const float4*)(Ap + kb + BK);
            a1 = *(const float4*)(Ap + kb + BK + 4);
            w0 = *(const float4*)(Wp + kb + BK);
            w1 = *(const float4*)(Wp + kb + BK + 4);
        }

        s16x8 ah = *(const s16x8*)&Ah[buf][afo];
        s16x8 am = *(const s16x8*)&Am[buf][afo];
        #pragma unroll
        for (int nt = 0; nt < 4; ++nt) {
            const int bfo = (nt * 64 + lane) * 8;
            s16x8 bh = *(const s16x8*)&Wh[buf][bfo];
            s16x8 bm = *(const s16x8*)&Wm[buf][bfo];
            accM[nt] = __builtin_amdgcn_mfma_f32_16x16x32_bf16(ah, bh, accM[nt], 0, 0, 0);
            accS[nt] = __builtin_amdgcn_mfma_f32_16x16x32_bf16(ah, bm, accS[nt], 0, 0, 0);
            accS[nt] = __builtin_amdgcn_mfma_f32_16x16x32_bf16(am, bh, accS[nt], 0, 0, 0);
        }

        if (more) {
            dwrite(Ah[buf ^ 1], Am[buf ^ 1], slot, a0, a1);
            dwrite(Wh[buf ^ 1], Wm[buf ^ 1], slot, w0, w1);
        }
        __syncthreads();
    }

    // C/D layout: col = lane&15, row = (lane>>4)*4 + reg  [m89-verified]
    #pragma unroll
    for (int nt = 0; nt < 4; ++nt)
        #pragma unroll
        for (int r = 0; r < 4; ++r)
            lg[wv * 16 + (lane >> 4) * 4 + r][nt * 16 + (lane & 15)]
                = accM[nt][r] + 0.00390625f * accS[nt][r];
    __syncthreads();

    // ---- per-row epilogue: 4 waves x 16 rows (proven in round 1) ----
    float* out_idx   = out;
    float* out_w     = out + 2 * GS;
    float* out_probs = out + 4 * GS + 1;

    const float blane = bias[lane];
    float impL = 0.f, cntL = 0.f;

    for (int rr = 0; rr < 16; ++rr) {
        const int r = (wv << 4) + rr;
        const size_t row = (size_t)row0 + r;
        float v = lg[r][lane] + blane + noise[row * EXP + lane];

        float m = v;
        #pragma unroll
        for (int off = 32; off >= 1; off >>= 1)
            m = fmaxf(m, __shfl_xor(m, off));
        float e = expf(v - m);
        float s = e;
        #pragma unroll
        for (int off = 32; off >= 1; off >>= 1)
            s += __shfl_xor(s, off);
        float p = e / s;

        out_probs[row * EXP + lane] = p;
        impL += p;
        cntL += (p > 0.f) ? 1.f : 0.f;

        float v1 = p; int i1 = lane;
        #pragma unroll
        for (int off = 32; off >= 1; off >>= 1) {
            float ov = __shfl_xor(v1, off);
            int   oi = __shfl_xor(i1, off);
            if (ov > v1 || (ov == v1 && oi < i1)) { v1 = ov; i1 = oi; }
        }
        float v2 = (lane == i1) ? -1.f : p; int i2 = lane;
        #pragma unroll
        for (int off = 32; off >= 1; off >>= 1) {
            float ov = __shfl_xor(v2, off);
            int   oi = __shfl_xor(i2, off);
            if (ov > v2 || (ov == v2 && oi < i2)) { v2 = ov; i2 = oi; }
        }
        if (lane == 0) {
            float denom = v1 + v2 + 1e-9f;
            out_idx[row * 2 + 0] = (float)i1;
            out_idx[row * 2 + 1] = (float)i2;
            out_w[row * 2 + 0] = v1 / denom;
            out_w[row * 2 + 1] = v2 / denom;
        }
    }

    red[wv][lane]     = impL;
    red[4 + wv][lane] = cntL;
    __syncthreads();
    if (tid < EXP) {
        float t1 = red[0][tid] + red[1][tid] + red[2][tid] + red[3][tid];
        float t2 = red[4][tid] + red[5][tid] + red[6][tid] + red[7][tid];
        atomicAdd(&ws[tid], t1);
        atomicAdd(&ws[EXP + tid], t2);
    }
}

__global__ void aux_kernel(const float* __restrict__ ws, float* __restrict__ out)
{
    const int lane = threadIdx.x;  // 64 threads
    float x = ws[lane] * ws[EXP + lane];   // importance * load
    float s = x;
    #pragma unroll
    for (int off = 32; off >= 1; off >>= 1)
        s += __shfl_xor(s, off);
    float mean = s * (1.f / 64.f);
    float d = x - mean;
    float ss = d * d;
    #pragma unroll
    for (int off = 32; off >= 1; off >>= 1)
        ss += __shfl_xor(ss, off);
    if (lane == 0)
        out[4 * GS] = 0.01f * (ss / 63.f);   // unbiased var * 0.01
}

extern "C" void kernel_launch(void* const* d_in, const int* in_sizes, int n_in,
                              void* d_out, int out_size, void* d_ws, size_t ws_size,
                              hipStream_t stream)
{
    const float* tokens = (const float*)d_in[0];
    const float* noise  = (const float*)d_in[1];
    const float* W      = (const float*)d_in[2];
    const float* bias   = (const float*)d_in[3];
    float* out = (float*)d_out;
    float* ws  = (float*)d_ws;

    hipMemsetAsync(ws, 0, 2 * EXP * sizeof(float), stream);
    router_kernel<<<GS / BM, 256, 0, stream>>>(tokens, noise, W, bias, out, ws);
    aux_kernel<<<1, 64, 0, stream>>>(ws, out);
}